// Round 6
// baseline (259.461 us; speedup 1.0000x reference)
//
#include <hip/hip_runtime.h>
#include <hip/hip_bf16.h>
#include <stdint.h>

// Router GEMM: out[8192,768] (fp32) = X[8192,6144] @ W[768,6144]^T
// KEY DISCOVERY (rounds 0-5 statistical analysis): device input buffers are
// FP32 UPCASTS of the bf16 arrays (numpy reference path can't hold bf16).
// Read as float*, truncate to bf16 in-register (exact: low 16 bits are 0),
// then run the proven MFMA structure (rounds 1<->4 bit-agreement verified the
// fragment/epilogue conventions).
// BM=64, BN=128, BK=32, 256 threads (4 waves, 2x2), reg-staged LDS.

#define M_DIM 8192
#define N_DIM 768
#define K_DIM 6144

#define BM 64
#define BN 128
#define BK 32

typedef __bf16 bf16x8 __attribute__((ext_vector_type(8)));
typedef float f32x4 __attribute__((ext_vector_type(4)));

static __device__ __forceinline__ __bf16 bf16_trunc(float f) {
    uint32_t u = __builtin_bit_cast(uint32_t, f);
    uint16_t h = (uint16_t)(u >> 16);   // exact for bf16-upcast data
    return __builtin_bit_cast(__bf16, h);
}

static __device__ __forceinline__ bf16x8 pack_bf16x8(f32x4 a, f32x4 b) {
    bf16x8 r;
    #pragma unroll
    for (int j = 0; j < 4; ++j) {
        r[j]     = bf16_trunc(a[j]);
        r[4 + j] = bf16_trunc(b[j]);
    }
    return r;
}

__global__ __launch_bounds__(256, 4) void router_gemm_f32in_kernel(
    const float* __restrict__ X, const float* __restrict__ W,
    float* __restrict__ out)
{
    __shared__ __align__(16) __bf16 As[BM * BK];   // 4 KiB
    __shared__ __align__(16) __bf16 Bs[BN * BK];   // 8 KiB

    const int tid  = threadIdx.x;
    const int w    = tid >> 6;        // wave 0..3
    const int lane = tid & 63;

    const int bid = blockIdx.x;
    const int bn  = bid % (N_DIM / BN);   // 0..5
    const int bm  = bid / (N_DIM / BN);   // 0..127

    const int wr = w >> 1;            // wave row 0..1 (32 m-rows)
    const int wc = w & 1;             // wave col 0..1 (64 n-cols)

    const int lrow = lane & 15;
    const int kg   = lane >> 4;

    // staging: unit u covers tile elements [8u, 8u+8): row=u>>2, k=(u&3)*8
    const int srow = tid >> 2;            // 0..63
    const int sk   = (tid & 3) * 8;       // 0,8,16,24

    const float* Xg = X + (size_t)(bm * BM) * K_DIM;
    const float* Wg = W + (size_t)(bn * BN) * K_DIM;

    f32x4 acc[2][4] = {};

    for (int k0 = 0; k0 < K_DIM; k0 += BK) {
        __syncthreads();   // prior LDS reads done before overwrite

        // fp32 global loads (16B each), truncate-pack to bf16x8
        const float* xa = Xg + (size_t)srow * K_DIM + (k0 + sk);
        f32x4 a0 = *(const f32x4*)(xa);
        f32x4 a1 = *(const f32x4*)(xa + 4);

        const float* wb0 = Wg + (size_t)srow * K_DIM + (k0 + sk);
        f32x4 b00 = *(const f32x4*)(wb0);
        f32x4 b01 = *(const f32x4*)(wb0 + 4);

        const float* wb1 = Wg + (size_t)(srow + 64) * K_DIM + (k0 + sk);
        f32x4 b10 = *(const f32x4*)(wb1);
        f32x4 b11 = *(const f32x4*)(wb1 + 4);

        *(bf16x8*)(As + tid * 8)         = pack_bf16x8(a0, a1);
        *(bf16x8*)(Bs + tid * 8)         = pack_bf16x8(b00, b01);
        *(bf16x8*)(Bs + (tid + 256) * 8) = pack_bf16x8(b10, b11);

        __syncthreads();

        bf16x8 a[2], b[4];
        #pragma unroll
        for (int mf = 0; mf < 2; ++mf)
            a[mf] = *(const bf16x8*)(As + (wr * 32 + mf * 16 + lrow) * BK + kg * 8);
        #pragma unroll
        for (int nf = 0; nf < 4; ++nf)
            b[nf] = *(const bf16x8*)(Bs + (wc * 64 + nf * 16 + lrow) * BK + kg * 8);

        #pragma unroll
        for (int mf = 0; mf < 2; ++mf)
            #pragma unroll
            for (int nf = 0; nf < 4; ++nf)
                acc[mf][nf] = __builtin_amdgcn_mfma_f32_16x16x32_bf16(
                    a[mf], b[nf], acc[mf][nf], 0, 0, 0);
    }

    // epilogue: C/D layout col = lane&15, row = (lane>>4)*4 + reg
    // (validated by round-3 runtime probe)
    const int orow0 = bm * BM + wr * 32 + kg * 4;
    const int ocol0 = bn * BN + wc * 64 + lrow;
    #pragma unroll
    for (int mf = 0; mf < 2; ++mf)
        #pragma unroll
        for (int nf = 0; nf < 4; ++nf)
            #pragma unroll
            for (int r = 0; r < 4; ++r)
                out[(size_t)(orow0 + mf * 16 + r) * N_DIM + (ocol0 + nf * 16)] =
                    acc[mf][nf][r];
}

extern "C" void kernel_launch(void* const* d_in, const int* in_sizes, int n_in,
                              void* d_out, int out_size, void* d_ws, size_t ws_size,
                              hipStream_t stream) {
    // in_sizes are element counts; hidden_states has 8192*6144 elements.
    const float* X;
    const float* W;
    if (in_sizes[0] == M_DIM * K_DIM) {
        X = (const float*)d_in[0];
        W = (const float*)d_in[1];
    } else {
        X = (const float*)d_in[1];
        W = (const float*)d_in[0];
    }
    float* out = (float*)d_out;                 // [8192, 768] fp32

    const int grid = (M_DIM / BM) * (N_DIM / BN);   // 128 * 6 = 768 blocks
    hipLaunchKernelGGL(router_gemm_f32in_kernel, dim3(grid), dim3(256), 0, stream,
                       X, W, out);
}

// Round 7
// 204.068 us; speedup vs baseline: 1.2714x; 1.2714x over previous
//
#include <hip/hip_runtime.h>
#include <hip/hip_bf16.h>
#include <stdint.h>

// Router GEMM: out[8192,768] (fp32) = X[8192,6144] @ W[768,6144]^T
// Device buffers hold FP32 upcasts of the bf16 data (round-6 discovery).
// Round 7: L2-BW-oriented rework:
//   - BM=BN=128, BK=32 (CU<-L2 traffic 3.6GB -> 2.4GB)
//   - register prefetch pipeline (issue loads -> frag-read+MFMA -> barrier ->
//     cvt+ds_write -> barrier), hides load latency (T14)
//   - LDS XOR slot swizzle on both write and read (8-way -> free 2-way)
//   - XCD-chunked block swizzle (384 blocks = 48/XCD, X-panel sharers co-L2)

#define M_DIM 8192
#define N_DIM 768
#define K_DIM 6144

#define BM 128
#define BN 128
#define BK 32
#define NT (K_DIM / BK)          // 192 K-steps

typedef __bf16 bf16x8 __attribute__((ext_vector_type(8)));
typedef float f32x4 __attribute__((ext_vector_type(4)));

static __device__ __forceinline__ __bf16 bf16_trunc(float f) {
    uint32_t u = __builtin_bit_cast(uint32_t, f);
    return __builtin_bit_cast(__bf16, (uint16_t)(u >> 16));  // exact on upcast data
}

static __device__ __forceinline__ bf16x8 pack_bf16x8(f32x4 a, f32x4 b) {
    bf16x8 r;
    #pragma unroll
    for (int j = 0; j < 4; ++j) {
        r[j]     = bf16_trunc(a[j]);
        r[4 + j] = bf16_trunc(b[j]);
    }
    return r;
}

__global__ __launch_bounds__(256, 3) void router_gemm_pf_kernel(
    const float* __restrict__ X, const float* __restrict__ W,
    float* __restrict__ out)
{
    // LDS tiles [128 rows][32 k] bf16, 16B slots XOR-swizzled by (row&3)
    __shared__ __align__(16) __bf16 As[BM * BK];   // 8 KiB
    __shared__ __align__(16) __bf16 Bs[BN * BK];   // 8 KiB

    const int tid  = threadIdx.x;
    const int w    = tid >> 6;
    const int lane = tid & 63;

    // XCD-chunked bijective swizzle: 384 blocks, 8 XCDs, 48/chunk; bn fast.
    const int nb = (blockIdx.x & 7) * 48 + (blockIdx.x >> 3);
    const int bn = nb % (N_DIM / BN);   // 0..5
    const int bm = nb / (N_DIM / BN);   // 0..63

    const int wr = w >> 1;              // wave row 0..1 (64 m-rows)
    const int wc = w & 1;               // wave col 0..1 (64 n-cols)

    const int lrow = lane & 15;
    const int kg   = lane >> 4;

    // staging: unit u in [0,512) per tile; row=u>>2, k8=u&3 (8 bf16 per unit)
    // thread handles units {tid, tid+256} of each tile (rows srow, srow+64).
    const int srow = tid >> 2;          // 0..63
    const int sk8  = tid & 3;           // k-slot 0..3
    const int wslot0 = (sk8 ^ (srow & 3)) * 8;   // swizzled elem offset (same for srow+64)

    const float* Xg = X + (size_t)(bm * BM) * K_DIM;
    const float* Wg = W + (size_t)(bn * BN) * K_DIM;
    const float* xrow0 = Xg + (size_t)srow * K_DIM + sk8 * 8;
    const float* xrow1 = xrow0 + (size_t)64 * K_DIM;
    const float* wrow0 = Wg + (size_t)srow * K_DIM + sk8 * 8;
    const float* wrow1 = wrow0 + (size_t)64 * K_DIM;

    f32x4 pr[8];

    #define ISSUE_LOADS(K0)                                  \
        do {                                                 \
            pr[0] = *(const f32x4*)(xrow0 + (K0));           \
            pr[1] = *(const f32x4*)(xrow0 + (K0) + 4);       \
            pr[2] = *(const f32x4*)(xrow1 + (K0));           \
            pr[3] = *(const f32x4*)(xrow1 + (K0) + 4);       \
            pr[4] = *(const f32x4*)(wrow0 + (K0));           \
            pr[5] = *(const f32x4*)(wrow0 + (K0) + 4);       \
            pr[6] = *(const f32x4*)(wrow1 + (K0));           \
            pr[7] = *(const f32x4*)(wrow1 + (K0) + 4);       \
        } while (0)

    #define WRITE_LDS()                                                         \
        do {                                                                    \
            *(bf16x8*)(As + srow * BK + wslot0)        = pack_bf16x8(pr[0], pr[1]); \
            *(bf16x8*)(As + (srow + 64) * BK + wslot0) = pack_bf16x8(pr[2], pr[3]); \
            *(bf16x8*)(Bs + srow * BK + wslot0)        = pack_bf16x8(pr[4], pr[5]); \
            *(bf16x8*)(Bs + (srow + 64) * BK + wslot0) = pack_bf16x8(pr[6], pr[7]); \
        } while (0)

    // prologue: stage tile 0
    ISSUE_LOADS(0);
    WRITE_LDS();
    __syncthreads();

    f32x4 acc[4][4] = {};

    // frag read slot: row = (wr|wc)*64 + f*16 + lrow -> row&3 == lrow&3
    const int rslot = (kg ^ (lrow & 3)) * 8;
    const int arow0 = wr * 64 + lrow;
    const int brow0 = wc * 64 + lrow;

    for (int t = 0; t < NT; ++t) {
        if (t + 1 < NT) ISSUE_LOADS((t + 1) * BK);

        bf16x8 a[4], b[4];
        #pragma unroll
        for (int mf = 0; mf < 4; ++mf)
            a[mf] = *(const bf16x8*)(As + (arow0 + mf * 16) * BK + rslot);
        #pragma unroll
        for (int nf = 0; nf < 4; ++nf)
            b[nf] = *(const bf16x8*)(Bs + (brow0 + nf * 16) * BK + rslot);

        #pragma unroll
        for (int mf = 0; mf < 4; ++mf)
            #pragma unroll
            for (int nf = 0; nf < 4; ++nf)
                acc[mf][nf] = __builtin_amdgcn_mfma_f32_16x16x32_bf16(
                    a[mf], b[nf], acc[mf][nf], 0, 0, 0);

        __syncthreads();                  // all frag reads done
        if (t + 1 < NT) WRITE_LDS();      // vmcnt wait lands here (post-MFMA)
        __syncthreads();                  // staging visible
    }

    // epilogue: C/D layout col = lane&15, row = (lane>>4)*4 + reg (verified)
    const int orow0 = bm * BM + wr * 64 + kg * 4;
    const int ocol0 = bn * BN + wc * 64 + lrow;
    #pragma unroll
    for (int mf = 0; mf < 4; ++mf)
        #pragma unroll
        for (int nf = 0; nf < 4; ++nf)
            #pragma unroll
            for (int r = 0; r < 4; ++r)
                out[(size_t)(orow0 + mf * 16 + r) * N_DIM + (ocol0 + nf * 16)] =
                    acc[mf][nf][r];

    #undef ISSUE_LOADS
    #undef WRITE_LDS
}

extern "C" void kernel_launch(void* const* d_in, const int* in_sizes, int n_in,
                              void* d_out, int out_size, void* d_ws, size_t ws_size,
                              hipStream_t stream) {
    const float* X;
    const float* W;
    if (in_sizes[0] == M_DIM * K_DIM) {
        X = (const float*)d_in[0];
        W = (const float*)d_in[1];
    } else {
        X = (const float*)d_in[1];
        W = (const float*)d_in[0];
    }
    float* out = (float*)d_out;

    const int grid = (M_DIM / BM) * (N_DIM / BN);   // 64 * 6 = 384 blocks
    hipLaunchKernelGGL(router_gemm_pf_kernel, dim3(grid), dim3(256), 0, stream,
                       X, W, out);
}

// Round 8
// 160.875 us; speedup vs baseline: 1.6128x; 1.2685x over previous
//
#include <hip/hip_runtime.h>
#include <hip/hip_bf16.h>
#include <stdint.h>

// Router GEMM: out[8192,768] (fp32) = X[8192,6144] @ W[768,6144]^T
// Device buffers hold FP32 upcasts of the bf16 data (round-6 discovery).
// Round 8: SPLIT-K=2 at constant tile (BM=BN=128) -> 768 blocks = 3/CU.
//   - occupancy experiment: traffic unchanged (2.4GB), TLP doubled
//   - zero-init out via hipMemsetAsync + relaxed fp32 atomic-add epilogue
//   - XCD grouping: each XCD owns {8 bm x 6 bn x 2 ks} -> X panels cross
//     the fabric once and are shared by 12 co-resident blocks per XCD
//   - register-prefetch pipeline + LDS XOR swizzle kept from round 7

#define M_DIM 8192
#define N_DIM 768
#define K_DIM 6144

#define BM 128
#define BN 128
#define BK 32
#define SPLITK 2
#define KSEG (K_DIM / SPLITK)    // 3072 per block
#define NT (KSEG / BK)           // 96 K-steps

typedef __bf16 bf16x8 __attribute__((ext_vector_type(8)));
typedef float f32x4 __attribute__((ext_vector_type(4)));

static __device__ __forceinline__ __bf16 bf16_trunc(float f) {
    uint32_t u = __builtin_bit_cast(uint32_t, f);
    return __builtin_bit_cast(__bf16, (uint16_t)(u >> 16));  // exact on upcast data
}

static __device__ __forceinline__ bf16x8 pack_bf16x8(f32x4 a, f32x4 b) {
    bf16x8 r;
    #pragma unroll
    for (int j = 0; j < 4; ++j) {
        r[j]     = bf16_trunc(a[j]);
        r[4 + j] = bf16_trunc(b[j]);
    }
    return r;
}

__global__ __launch_bounds__(256, 3) void router_gemm_sk_kernel(
    const float* __restrict__ X, const float* __restrict__ W,
    float* __restrict__ out)
{
    __shared__ __align__(16) __bf16 As[BM * BK];   // 8 KiB
    __shared__ __align__(16) __bf16 Bs[BN * BK];   // 8 KiB

    const int tid  = threadIdx.x;
    const int w    = tid >> 6;
    const int lane = tid & 63;

    // XCD decode: consecutive blockIdx round-robin across 8 XCDs.
    // XCD x gets slots 0..95 covering {bmi 0..7} x {bn 0..5} x {ks 0..1};
    // bm = x*8 + bmi  -> each X panel lives on exactly one XCD.
    const int xcd  = blockIdx.x & 7;
    const int slot = blockIdx.x >> 3;      // 0..95
    const int bmi  = slot & 7;
    const int tt   = slot >> 3;            // 0..11
    const int bn   = tt % 6;
    const int ks   = tt / 6;               // 0..1
    const int bm   = xcd * 8 + bmi;        // 0..63

    const int kbase = ks * KSEG;

    const int wr = w >> 1;                 // wave row 0..1 (64 m-rows)
    const int wc = w & 1;                  // wave col 0..1 (64 n-cols)

    const int lrow = lane & 15;
    const int kg   = lane >> 4;

    // staging: unit u in [0,512) per tile; row=u>>2, k8=u&3 (8 bf16 per unit)
    const int srow = tid >> 2;             // 0..63
    const int sk8  = tid & 3;              // k-slot 0..3
    const int wslot0 = (sk8 ^ (srow & 3)) * 8;   // XOR-swizzled elem offset

    const float* Xg = X + (size_t)(bm * BM) * K_DIM;
    const float* Wg = W + (size_t)(bn * BN) * K_DIM;
    const float* xrow0 = Xg + (size_t)srow * K_DIM + sk8 * 8;
    const float* xrow1 = xrow0 + (size_t)64 * K_DIM;
    const float* wrow0 = Wg + (size_t)srow * K_DIM + sk8 * 8;
    const float* wrow1 = wrow0 + (size_t)64 * K_DIM;

    f32x4 pr[8];

    #define ISSUE_LOADS(K0)                                  \
        do {                                                 \
            pr[0] = *(const f32x4*)(xrow0 + (K0));           \
            pr[1] = *(const f32x4*)(xrow0 + (K0) + 4);       \
            pr[2] = *(const f32x4*)(xrow1 + (K0));           \
            pr[3] = *(const f32x4*)(xrow1 + (K0) + 4);       \
            pr[4] = *(const f32x4*)(wrow0 + (K0));           \
            pr[5] = *(const f32x4*)(wrow0 + (K0) + 4);       \
            pr[6] = *(const f32x4*)(wrow1 + (K0));           \
            pr[7] = *(const f32x4*)(wrow1 + (K0) + 4);       \
        } while (0)

    #define WRITE_LDS()                                                         \
        do {                                                                    \
            *(bf16x8*)(As + srow * BK + wslot0)        = pack_bf16x8(pr[0], pr[1]); \
            *(bf16x8*)(As + (srow + 64) * BK + wslot0) = pack_bf16x8(pr[2], pr[3]); \
            *(bf16x8*)(Bs + srow * BK + wslot0)        = pack_bf16x8(pr[4], pr[5]); \
            *(bf16x8*)(Bs + (srow + 64) * BK + wslot0) = pack_bf16x8(pr[6], pr[7]); \
        } while (0)

    ISSUE_LOADS(kbase);
    WRITE_LDS();
    __syncthreads();

    f32x4 acc[4][4] = {};

    const int rslot = (kg ^ (lrow & 3)) * 8;
    const int arow0 = wr * 64 + lrow;
    const int brow0 = wc * 64 + lrow;

    for (int t = 0; t < NT; ++t) {
        if (t + 1 < NT) ISSUE_LOADS(kbase + (t + 1) * BK);

        bf16x8 a[4], b[4];
        #pragma unroll
        for (int mf = 0; mf < 4; ++mf)
            a[mf] = *(const bf16x8*)(As + (arow0 + mf * 16) * BK + rslot);
        #pragma unroll
        for (int nf = 0; nf < 4; ++nf)
            b[nf] = *(const bf16x8*)(Bs + (brow0 + nf * 16) * BK + rslot);

        #pragma unroll
        for (int mf = 0; mf < 4; ++mf)
            #pragma unroll
            for (int nf = 0; nf < 4; ++nf)
                acc[mf][nf] = __builtin_amdgcn_mfma_f32_16x16x32_bf16(
                    a[mf], b[nf], acc[mf][nf], 0, 0, 0);

        __syncthreads();
        if (t + 1 < NT) WRITE_LDS();
        __syncthreads();
    }

    // epilogue: relaxed device-scope fp32 atomic add (out zero-initialized
    // by hipMemsetAsync in kernel_launch). C/D layout verified (m89 + probe).
    const int orow0 = bm * BM + wr * 64 + kg * 4;
    const int ocol0 = bn * BN + wc * 64 + lrow;
    #pragma unroll
    for (int mf = 0; mf < 4; ++mf)
        #pragma unroll
        for (int nf = 0; nf < 4; ++nf)
            #pragma unroll
            for (int r = 0; r < 4; ++r) {
                float* o = out + (size_t)(orow0 + mf * 16 + r) * N_DIM
                               + (ocol0 + nf * 16);
                __hip_atomic_fetch_add(o, acc[mf][nf][r],
                                       __ATOMIC_RELAXED, __HIP_MEMORY_SCOPE_AGENT);
            }

    #undef ISSUE_LOADS
    #undef WRITE_LDS
}

extern "C" void kernel_launch(void* const* d_in, const int* in_sizes, int n_in,
                              void* d_out, int out_size, void* d_ws, size_t ws_size,
                              hipStream_t stream) {
    const float* X;
    const float* W;
    if (in_sizes[0] == M_DIM * K_DIM) {
        X = (const float*)d_in[0];
        W = (const float*)d_in[1];
    } else {
        X = (const float*)d_in[1];
        W = (const float*)d_in[0];
    }
    float* out = (float*)d_out;

    // zero-init for atomic accumulation (async stream op: graph-capture-safe)
    hipMemsetAsync(out, 0, (size_t)M_DIM * N_DIM * sizeof(float), stream);

    const int grid = (M_DIM / BM) * (N_DIM / BN) * SPLITK;   // 64*6*2 = 768
    hipLaunchKernelGGL(router_gemm_sk_kernel, dim3(grid), dim3(256), 0, stream,
                       X, W, out);
}